// Round 6
// baseline (29.724 us; speedup 1.0000x reference)
//
#include <hip/hip_runtime.h>

#define CLS 512
#define NROWS 32768
#define WPB 4
#define NBLOCKS 1024   // 1024 blocks * 4 waves * 8 rows/wave = 32768 rows

// f32 add with DPP-shifted operand (VALU pipe, no DS/lgkmcnt).
template <int CTRL, int ROWM>
__device__ __forceinline__ float dpp_add(float x) {
  int s = __builtin_amdgcn_update_dpp(0, __float_as_int(x), CTRL, ROWM, 0xf, true);
  return x + __int_as_float(s);
}

// Standard wave64 sum: after this, lane 63 holds the full 64-lane sum.
__device__ __forceinline__ float wave_sum_dpp(float x) {
  x = dpp_add<0x111, 0xf>(x);  // row_shr:1
  x = dpp_add<0x112, 0xf>(x);  // row_shr:2
  x = dpp_add<0x114, 0xf>(x);  // row_shr:4
  x = dpp_add<0x118, 0xf>(x);  // row_shr:8
  x = dpp_add<0x142, 0xa>(x);  // row_bcast:15
  x = dpp_add<0x143, 0xc>(x);  // row_bcast:31 -> lane 63 = total
  return x;
}

// Contribution of 4 rows held in registers (valid in lane 63).
__device__ __forceinline__ float rows4_contrib(const float4* o, const int4* t) {
  float acc = 0.0f;
#pragma unroll
  for (int r = 0; r < 4; ++r) {
    float s_neg = 0.0f, s_pos = 0.0f, np = 0.0f;
#pragma unroll
    for (int k = 0; k < 2; ++k) {
      float4 ov = o[2 * r + k];
      int4   tv = t[2 * r + k];
      float vx[4] = {ov.x, ov.y, ov.z, ov.w};
      int   mx[4] = {tv.x, tv.y, tv.z, tv.w};
#pragma unroll
      for (int j = 0; j < 4; ++j) {
        float e = __expf(mx[j] ? -vx[j] : vx[j]);
        s_pos += mx[j] ? e : 0.0f;
        s_neg += mx[j] ? 0.0f : e;
        np    += mx[j] ? 1.0f : 0.0f;
      }
    }
    s_neg = wave_sum_dpp(s_neg);
    s_pos = wave_sum_dpp(s_pos);
    np    = wave_sum_dpp(np);
    float num = np * ((float)CLS - np);
    if (num == 0.0f) num = (float)CLS;
    acc += s_neg * s_pos / num;   // valid in lane 63
  }
  return acc;
}

__global__ __launch_bounds__(256) void lr_main_kernel(
    const float* __restrict__ out, const int* __restrict__ tgt,
    float* __restrict__ partial) {
  const int lane = threadIdx.x & 63;
  const int wid  = threadIdx.x >> 6;
  const int gw   = blockIdx.x * WPB + wid;          // 0..4095
  const size_t base = (size_t)gw * 8 * CLS;         // 8 consecutive rows per wave

  const float4* po = reinterpret_cast<const float4*>(out + base);
  const int4*   pt = reinterpret_cast<const int4*>(tgt + base);

  float4 oA[8], oB[8];
  int4   tA[8], tB[8];
#pragma unroll
  for (int r = 0; r < 4; ++r) {
    oA[2 * r]     = po[r * 128 + lane];
    oA[2 * r + 1] = po[r * 128 + 64 + lane];
    tA[2 * r]     = pt[r * 128 + lane];
    tA[2 * r + 1] = pt[r * 128 + 64 + lane];
  }
#pragma unroll
  for (int r = 0; r < 4; ++r) {
    oB[2 * r]     = po[(r + 4) * 128 + lane];
    oB[2 * r + 1] = po[(r + 4) * 128 + 64 + lane];
    tB[2 * r]     = pt[(r + 4) * 128 + lane];
    tB[2 * r + 1] = pt[(r + 4) * 128 + 64 + lane];
  }
  // Pin all 32 loads before any compute: loads are memory ops and cannot be
  // sunk past this clobber. Forces real MLP (VGPR should jump to ~150).
  asm volatile("" ::: "memory");

  float acc = rows4_contrib(oA, tA);   // B-group loads still in flight
  acc += rows4_contrib(oB, tB);

  __shared__ float sacc[WPB];
  if (lane == 63) sacc[wid] = acc;
  __syncthreads();
  if (threadIdx.x == 0)
    partial[blockIdx.x] = sacc[0] + sacc[1] + sacc[2] + sacc[3];
}

__global__ __launch_bounds__(256) void lr_final_kernel(
    const float* __restrict__ partial, float* __restrict__ out) {
  const int lane = threadIdx.x & 63;
  const int wid  = threadIdx.x >> 6;

  float s = 0.0f;
#pragma unroll
  for (int i = threadIdx.x; i < NBLOCKS; i += 256) s += partial[i];

#pragma unroll
  for (int m = 1; m < 64; m <<= 1) s += __shfl_xor(s, m);

  __shared__ float w[4];
  if (lane == 0) w[wid] = s;
  __syncthreads();
  if (threadIdx.x == 0) out[0] = w[0] + w[1] + w[2] + w[3];
}

extern "C" void kernel_launch(void* const* d_in, const int* in_sizes, int n_in,
                              void* d_out, int out_size, void* d_ws, size_t ws_size,
                              hipStream_t stream) {
  const float* output = (const float*)d_in[0];
  const int*   target = (const int*)d_in[1];
  float* partial = (float*)d_ws;          // NBLOCKS floats = 4 KiB
  float* loss    = (float*)d_out;

  lr_main_kernel<<<NBLOCKS, 256, 0, stream>>>(output, target, partial);
  lr_final_kernel<<<1, 256, 0, stream>>>(partial, loss);
}